// Round 13
// baseline (115.415 us; speedup 1.0000x reference)
//
#include <hip/hip_runtime.h>
#include <stdint.h>

#define Nd 8000
#define Nk 2000
#define FD 32
#define FK 16
#define HD 64
#define NH 8
#define KP 2048
#define NKB 64   // KP/32
#define LOG2E 1.44269504088896f
#define NSLOPE 0.2f

typedef float f4 __attribute__((ext_vector_type(4)));
typedef short s16x8 __attribute__((ext_vector_type(8)));
typedef int i4 __attribute__((ext_vector_type(4)));
typedef unsigned int u32;
typedef unsigned short u16;
typedef unsigned int u4v __attribute__((ext_vector_type(4)));

// ---- workspace layout (bytes), 16B aligned; total ~13.1 MB ----
#define WS_WHKB   0          // bf16 [8][64 kb][4 cc][64 lane][8 e] = 2 MB
#define WS_ESKP   2097152    // f32 [8][2048]  exp2(sk*log2e)
#define WS_ESKN   2162688    // f32 [8][2048]  exp2(0.2*sk*log2e)
#define WS_ESD    2228224    // f32 [8][8000][2]  {exp2(sd*log2e), exp2(0.2*sd*log2e)}
#define WS_ADJB   2740224    // u32 [8000][64] bitmask (bit = k%32, word = k/32)
#define WS_WFT    4788224    // bf16 [64 j][512 k]
#define WS_HP     4853760    // bf16 [8000][512]

__device__ inline u16 f2bf_rne(float f){
  u32 u = __float_as_uint(f);
  u32 r = u + 0x7fffu + ((u >> 16) & 1u);
  return (u16)(r >> 16);
}
__device__ inline float elu1(float x){
  return x > 0.f ? x : (__builtin_amdgcn_exp2f(x * LOG2E) - 1.f);
}

// ---------- adj [8000][2000] i32 -> bitmask; LDS-free, 2 words (256B) / thread ----------
__global__ __launch_bounds__(256) void k_adjb(const int* __restrict__ adj,
                                              u32* __restrict__ adjb){
  int id = blockIdx.x * 256 + threadIdx.x;   // 1000 blocks -> 256000 threads
  int w0 = id * 2;
  int n = w0 >> 6, c0 = w0 & 63;             // both words in same row (c0 even)
  int k0 = c0 * 32;
  const int* rowp = adj + n * Nk;
  u32 b0 = 0, b1 = 0;
  #pragma unroll
  for (int q = 0; q < 8; ++q) {              // 16 independent dwordx4 in flight
    int ka = min(k0 + q * 4, Nk - 4);
    int kb = min(k0 + 32 + q * 4, Nk - 4);
    i4 va = *(const i4*)(rowp + ka);
    i4 vb = *(const i4*)(rowp + kb);
    b0 |= (va[0] != 0 ? 1u : 0u) << (q * 4);
    b0 |= (va[1] != 0 ? 1u : 0u) << (q * 4 + 1);
    b0 |= (va[2] != 0 ? 1u : 0u) << (q * 4 + 2);
    b0 |= (va[3] != 0 ? 1u : 0u) << (q * 4 + 3);
    b1 |= (vb[0] != 0 ? 1u : 0u) << (q * 4);
    b1 |= (vb[1] != 0 ? 1u : 0u) << (q * 4 + 1);
    b1 |= (vb[2] != 0 ? 1u : 0u) << (q * 4 + 2);
    b1 |= (vb[3] != 0 ? 1u : 0u) << (q * 4 + 3);
  }
  int r0 = Nk - k0, r1 = Nk - k0 - 32;       // tail masks
  u32 t0 = (r0 >= 32) ? 0xFFFFFFFFu : ((r0 <= 0) ? 0u : ((1u << r0) - 1u));
  u32 t1 = (r1 >= 32) ? 0xFFFFFFFFu : ((r1 <= 0) ? 0u : ((1u << r1) - 1u));
  adjb[w0]     = b0 & t0;
  adjb[w0 + 1] = b1 & t1;
}

// ---------- fused prep: [0,512) whk(+hdock,wfT) | [512,1012) dsd ----------
__global__ __launch_bounds__(256) void k_prep(const float* __restrict__ rdrone,
                                              const float* __restrict__ rdock,
                                              const float* __restrict__ Wpd,
                                              const float* __restrict__ bpd,
                                              const float* __restrict__ Wpk,
                                              const float* __restrict__ bpk,
                                              const float* __restrict__ Wa,
                                              const float* __restrict__ a1,
                                              const float* __restrict__ a2,
                                              const float* __restrict__ Wf,
                                              float* __restrict__ out_hdock,
                                              u16* __restrict__ whkB,
                                              float* __restrict__ eskp,
                                              float* __restrict__ eskn,
                                              float* __restrict__ esd,
                                              u16* __restrict__ wfT){
  __shared__ __align__(16) char smem[13440];
  int b = blockIdx.x;
  int t = threadIdx.x;

  if (b < 512) {
    // ---- h_dock (-> output 1), WhkB bf16 fragments, esk; h==1 blocks also WfT ----
    int kt = b & 63, h = b >> 6;
    float* hs   = (float*)smem;            // [32][65]
    float* part = (float*)(smem + 8320);   // [32][8]
    u16*   ts   = (u16*)(smem + 9344);     // [64 f][32 k]
    if (h == 1) {
      int id = kt * 256 + t;
      #pragma unroll
      for (int i = 0; i < 2; ++i) {
        int ix = id * 2 + i;               // ix = j*512 + k
        int j = ix >> 9, k = ix & 511;
        wfT[ix] = f2bf_rne(Wf[k * HD + j]);
      }
    }
    {
      int r = t >> 3, f0 = (t & 7) * 8;
      int gk = kt * 32 + r;
      float v[8];
      if (gk < Nk) {
        #pragma unroll
        for (int q = 0; q < 8; ++q) v[q] = bpk[f0 + q];
        for (int j = 0; j < FK; ++j) {
          float x = rdock[gk * FK + j];
          #pragma unroll
          for (int q = 0; q < 8; ++q) v[q] += x * Wpk[j * HD + f0 + q];
        }
        #pragma unroll
        for (int q = 0; q < 8; ++q) v[q] = elu1(v[q]);
        if (h == 0) {
          #pragma unroll
          for (int q = 0; q < 8; ++q) out_hdock[gk * HD + f0 + q] = v[q];
        }
      } else {
        #pragma unroll
        for (int q = 0; q < 8; ++q) v[q] = 0.f;
      }
      #pragma unroll
      for (int q = 0; q < 8; ++q) hs[r * 65 + f0 + q] = v[q];
    }
    __syncthreads();
    {
      int kl = t & 31, fq = t >> 5;
      float acc[8];
      #pragma unroll
      for (int j = 0; j < 8; ++j) acc[j] = 0.f;
      for (int d = 0; d < HD; ++d) {
        float hv = hs[kl * 65 + d];
        const float* wr = Wa + (h * HD + d) * HD + fq * 8;
        #pragma unroll
        for (int j = 0; j < 8; ++j) acc[j] += hv * wr[j];
      }
      float ps = 0.f;
      #pragma unroll
      for (int j = 0; j < 8; ++j) ps += acc[j] * a2[h * HD + fq * 8 + j];
      part[kl * 8 + fq] = ps;
      #pragma unroll
      for (int j = 0; j < 8; ++j)
        ts[(fq * 8 + j) * 32 + kl] = f2bf_rne(acc[j]);
    }
    __syncthreads();
    if (t < 32) {
      float s = 0.f;
      #pragma unroll
      for (int q = 0; q < 8; ++q) s += part[t * 8 + q];
      float ss = s * LOG2E;
      eskp[h * KP + kt * 32 + t] = __builtin_amdgcn_exp2f(ss);
      eskn[h * KP + kt * 32 + t] = __builtin_amdgcn_exp2f(NSLOPE * ss);
    }
    {
      int cc = t >> 6, lane = t & 63, g = (t >> 4) & 3, c16 = t & 15;
      int f = cc * 16 + c16;
      u4v val = *(const u4v*)&ts[f * 32 + g * 8];
      *(u4v*)(whkB + (((h * NKB + kt) * 4 + cc) * 64 + lane) * 8) = val;
    }
    return;
  }
  {
    // ---- esd[h][n] = {exp2(sd_s), exp2(0.2*sd_s)}, sd_s = (h_drone . wa1_h)*log2e ----
    int bid = b - 512;
    float* wa1 = (float*)smem;             // [8][64]
    #pragma unroll
    for (int i = 0; i < 2; ++i) {
      int ix = t + i * 256;
      int h = ix >> 6, d = ix & 63;
      float s = 0.f;
      for (int f = 0; f < HD; ++f) s += Wa[(h * HD + d) * HD + f] * a1[h * HD + f];
      wa1[ix] = s;
    }
    __syncthreads();
    int r4 = t >> 6, d = t & 63;
    for (int rr = 0; rr < 4; ++rr) {
      int n = bid * 16 + r4 * 4 + rr;      // 500*16 = 8000 exact
      float acc = bpd[d];
      for (int j = 0; j < FD; ++j) acc += rdrone[n * FD + j] * Wpd[j * HD + d];
      float hd = elu1(acc);
      #pragma unroll
      for (int h = 0; h < NH; ++h) {
        float v = hd * wa1[h * HD + d];
        v += __shfl_xor(v, 1);  v += __shfl_xor(v, 2);  v += __shfl_xor(v, 4);
        v += __shfl_xor(v, 8);  v += __shfl_xor(v, 16); v += __shfl_xor(v, 32);
        if (d == 0) {
          float ss = v * LOG2E;
          esd[(h * Nd + n) * 2]     = __builtin_amdgcn_exp2f(ss);
          esd[(h * Nd + n) * 2 + 1] = __builtin_amdgcn_exp2f(NSLOPE * ss);
        }
      }
    }
  }
}

// ---------- main: masked softmax(leaky(sd+sk)) @ Whk via MFMA ----------
// grid 1000 = 125 nt x 8 h (h = bid&7 pins head to XCD). Block = 64 rows,
// wave w = 16 rows. P-path is transcendental-free:
//   p = max(esd_p*esk_p[k], esd_n*esk_n[k])   [leaky+exp2 factorized],
// masked via sbfe+and. B staged in LDS (2-slot, issue-early/write-late).
__global__ __launch_bounds__(256) void k_attn(const float* __restrict__ esd,
                                              const float* __restrict__ eskp,
                                              const float* __restrict__ eskn,
                                              const u16* __restrict__ whkB,
                                              const u32* __restrict__ adjb,
                                              u16* __restrict__ hp){
  int bid = blockIdx.x;
  int h = bid & 7, nt = bid >> 3;
  int t = threadIdx.x;
  int w = t >> 6, lane = t & 63, g = lane >> 4, c16 = lane & 15;
  int r0 = nt * 64 + w * 16;
  __shared__ u16 bslot[2][2048];     // 2 x 4KB B tiles
  __shared__ u16 ldshp[64 * 64];

  int rowA = r0 + c16;               // always < 8000
  float esdp = esd[(h * Nd + rowA) * 2];
  float esdn = esd[(h * Nd + rowA) * 2 + 1];
  f4 acc[4], accd;
  accd = (f4){0.f, 0.f, 0.f, 0.f};
  #pragma unroll
  for (int cc = 0; cc < 4; ++cc) acc[cc] = (f4){0.f, 0.f, 0.f, 0.f};
  s16x8 onesf = (s16x8)(short)((c16 == 0) ? 0x3F80 : 0);

  const u16* bb = whkB + h * (NKB * 4 * 64 * 8);
  const float* ekp = eskp + h * KP;
  const float* ekn = eskn + h * KP;
  const u32* ap = adjb + rowA * 64;
  int soff = w * 512 + lane * 8;     // this thread's stage slot offset (u16)

  // prologue: slot0 <- tile0 (direct), stag <- tile1 (regs)
  *(u4v*)&bslot[0][soff] = *(const u4v*)(bb + soff);
  u4v stag = *(const u4v*)(bb + 2048 + soff);
  f4 cp0 = *(const f4*)(ekp + g * 8);
  f4 cp1 = *(const f4*)(ekp + g * 8 + 4);
  f4 cn0 = *(const f4*)(ekn + g * 8);
  f4 cn1 = *(const f4*)(ekn + g * 8 + 4);
  u4v caw = *(const u4v*)(ap);
  __syncthreads();

  for (int kb4 = 0; kb4 < 16; ++kb4) {
    u4v naw = *(const u4v*)(ap + kb4 * 4 + 4);  // kb4=15 overreads 16B in-ws
    #pragma unroll
    for (int u = 0; u < 4; ++u) {
      int kb = kb4 * 4 + u;
      // issue-early: B tile kb+2 + next esk pair (tail overreads stay in-ws)
      u4v nx = *(const u4v*)(bb + (kb + 2) * 2048 + soff);
      const float* npp = ekp + (kb + 1) * 32 + g * 8;
      const float* npn = ekn + (kb + 1) * 32 + g * 8;
      f4 np0 = *(const f4*)npp;
      f4 np1 = *(const f4*)(npp + 4);
      f4 nn0 = *(const f4*)npn;
      f4 nn1 = *(const f4*)(npn + 4);

      u32 ab = (caw[u] >> (g * 8)) & 0xffu;
      union { s16x8 v; u32 d[4]; } af;
      {
        f4 q0 = __builtin_elementwise_max(cp0 * esdp, cn0 * esdn);
        f4 q1 = __builtin_elementwise_max(cp1 * esdp, cn1 * esdn);
        float p[8] = {q0[0], q0[1], q0[2], q0[3], q1[0], q1[1], q1[2], q1[3]};
        #pragma unroll
        for (int e = 0; e < 8; ++e) {
          int mk = __builtin_amdgcn_sbfe(ab, e, 1);        // 0 or -1
          p[e] = __uint_as_float(__float_as_uint(p[e]) & (u32)mk);
        }
        #pragma unroll
        for (int jj = 0; jj < 4; ++jj)
          asm("v_cvt_pk_bf16_f32 %0, %1, %2"
              : "=v"(af.d[jj]) : "v"(p[2 * jj]), "v"(p[2 * jj + 1]));
      }
      __syncthreads();                 // orders prev write->this read & read->overwrite
      *(u4v*)&bslot[(kb + 1) & 1][soff] = stag;            // write-late (kb=63: dead slot)
      s16x8 b0 = *(const s16x8*)&bslot[kb & 1][lane * 8];
      s16x8 b1 = *(const s16x8*)&bslot[kb & 1][512 + lane * 8];
      s16x8 b2 = *(const s16x8*)&bslot[kb & 1][1024 + lane * 8];
      s16x8 b3 = *(const s16x8*)&bslot[kb & 1][1536 + lane * 8];
      accd   = __builtin_amdgcn_mfma_f32_16x16x32_bf16(af.v, onesf, accd, 0, 0, 0);
      acc[0] = __builtin_amdgcn_mfma_f32_16x16x32_bf16(af.v, b0, acc[0], 0, 0, 0);
      acc[1] = __builtin_amdgcn_mfma_f32_16x16x32_bf16(af.v, b1, acc[1], 0, 0, 0);
      acc[2] = __builtin_amdgcn_mfma_f32_16x16x32_bf16(af.v, b2, acc[2], 0, 0, 0);
      acc[3] = __builtin_amdgcn_mfma_f32_16x16x32_bf16(af.v, b3, acc[3], 0, 0, 0);
      stag = nx;
      cp0 = np0; cp1 = np1; cn0 = nn0; cn1 = nn1;
    }
    caw = naw;
  }

  // epilogue: den for row g*4+j lives in lane g*16 reg j -> broadcast
  #pragma unroll
  for (int j = 0; j < 4; ++j) {
    float den = __shfl(accd[j], lane & 48);
    float linv = (den > 0.f) ? 1.f / den : 0.f;
    #pragma unroll
    for (int cc = 0; cc < 4; ++cc) {
      float o = acc[cc][j] * linv;
      ldshp[(w * 16 + g * 4 + j) * 64 + cc * 16 + c16] = f2bf_rne(elu1(o));
    }
  }
  __syncthreads();
  {
    int r = t >> 2, q = t & 3;           // 64 rows x 4 chunks of 16 u16
    int row = nt * 64 + r;
    u16* dst = hp + row * 512 + h * 64 + q * 16;
    const u16* src = ldshp + r * 64 + q * 16;
    *(u4v*)(dst)     = *(const u4v*)(src);
    *(u4v*)(dst + 8) = *(const u4v*)(src + 8);
  }
}

// ---------- epilogue: out_drone = hp @ Wf + bf; wave = 16 rows x 16 cols ----------
__global__ __launch_bounds__(256) void k_out(const u16* __restrict__ hp,
                                             const u16* __restrict__ wfT,
                                             const float* __restrict__ bfv,
                                             float* __restrict__ out){
  int t = threadIdx.x;
  int w = t >> 6, lane = t & 63, g = lane >> 4, c16 = lane & 15;
  int r0 = blockIdx.x * 16;  // grid 500 -> 8000 exact
  f4 acc = (f4){0.f, 0.f, 0.f, 0.f};
  const u16* ap = hp + (r0 + c16) * 512 + g * 8;
  const u16* bp = wfT + (w * 16 + c16) * 512 + g * 8;
  #pragma unroll 4
  for (int kb = 0; kb < 16; ++kb) {
    s16x8 a = *(const s16x8*)(ap + kb * 32);
    s16x8 b = *(const s16x8*)(bp + kb * 32);
    acc = __builtin_amdgcn_mfma_f32_16x16x32_bf16(a, b, acc, 0, 0, 0);
  }
  float bias = bfv[w * 16 + c16];
  #pragma unroll
  for (int j = 0; j < 4; ++j)
    out[(r0 + g * 4 + j) * HD + w * 16 + c16] = acc[j] + bias;
}

extern "C" void kernel_launch(void* const* d_in, const int* in_sizes, int n_in,
                              void* d_out, int out_size, void* d_ws, size_t ws_size,
                              hipStream_t stream) {
  const float* raw_drone = (const float*)d_in[0];
  const float* raw_dock  = (const float*)d_in[1];
  const int*   adj       = (const int*)d_in[2];
  const float* Wpd = (const float*)d_in[3];
  const float* bpd = (const float*)d_in[4];
  const float* Wpk = (const float*)d_in[5];
  const float* bpk = (const float*)d_in[6];
  const float* Wa  = (const float*)d_in[7];
  const float* a1  = (const float*)d_in[8];
  const float* a2  = (const float*)d_in[9];
  const float* Wf  = (const float*)d_in[10];
  const float* bfb = (const float*)d_in[11];
  float* out = (float*)d_out;
  float* out_hdock = out + Nd * HD;

  char* ws = (char*)d_ws;
  u16*   whkB = (u16*)(ws + WS_WHKB);
  float* eskp = (float*)(ws + WS_ESKP);
  float* eskn = (float*)(ws + WS_ESKN);
  float* esd  = (float*)(ws + WS_ESD);
  u32*   adjb = (u32*)(ws + WS_ADJB);
  u16*   wfT  = (u16*)(ws + WS_WFT);
  u16*   hp   = (u16*)(ws + WS_HP);

  k_adjb<<<1000, 256, 0, stream>>>(adj, adjb);
  k_prep<<<1012, 256, 0, stream>>>(raw_drone, raw_dock, Wpd, bpd, Wpk, bpk,
                                   Wa, a1, a2, Wf, out_hdock, whkB,
                                   eskp, eskn, esd, wfT);
  k_attn<<<1000, 256, 0, stream>>>(esd, eskp, eskn, whkB, adjb, hp);
  k_out <<<500, 256, 0, stream>>>(hp, wfT, bfb, out);
}

// Round 15
// 106.982 us; speedup vs baseline: 1.0788x; 1.0788x over previous
//
#include <hip/hip_runtime.h>
#include <stdint.h>

#define Nd 8000
#define Nk 2000
#define FD 32
#define FK 16
#define HD 64
#define NH 8
#define KP 2048
#define NKB 64   // KP/32
#define LOG2E 1.44269504088896f
#define NSLOPE 0.2f

typedef float f4 __attribute__((ext_vector_type(4)));
typedef short s16x8 __attribute__((ext_vector_type(8)));
typedef int i4 __attribute__((ext_vector_type(4)));
typedef unsigned int u32;
typedef unsigned short u16;
typedef unsigned int u4v __attribute__((ext_vector_type(4)));

// ---- workspace layout (bytes), 16B aligned; total ~12.7 MB ----
#define WS_WHKB   0          // bf16 [8][64 kb][4 cc][64 lane][8 e] = 2 MB
#define WS_SK     2097152    // f32 [8][2048] (pre-scaled by log2e)
#define WS_SD     2162688    // f32 [8][8000] (pre-scaled by log2e)
#define WS_ADJB   2418688    // u32 [8000][64] bitmask (bit = k%32, word = k/32)
#define WS_WFT    4466688    // bf16 [64 j][512 k]
#define WS_HP     4532224    // bf16 [8000][512]

__device__ inline u16 f2bf_rne(float f){
  u32 u = __float_as_uint(f);
  u32 r = u + 0x7fffu + ((u >> 16) & 1u);
  return (u16)(r >> 16);
}
__device__ inline float elu1(float x){
  return x > 0.f ? x : (__builtin_amdgcn_exp2f(x * LOG2E) - 1.f);
}

// ---------- fused prep: [0,1000) adjb | [1000,1512) whk(+hdock,wfT) | [1512,2012) dsd ----------
// Phase code byte-identical to R12's k_adjb/k_prep; only the block map changed.
__global__ __launch_bounds__(256) void k_prep(const float* __restrict__ rdrone,
                                              const float* __restrict__ rdock,
                                              const int*   __restrict__ adj,
                                              const float* __restrict__ Wpd,
                                              const float* __restrict__ bpd,
                                              const float* __restrict__ Wpk,
                                              const float* __restrict__ bpk,
                                              const float* __restrict__ Wa,
                                              const float* __restrict__ a1,
                                              const float* __restrict__ a2,
                                              const float* __restrict__ Wf,
                                              float* __restrict__ out_hdock,
                                              u16* __restrict__ whkB,
                                              float* __restrict__ sk,
                                              float* __restrict__ sd,
                                              u32* __restrict__ adjb,
                                              u16* __restrict__ wfT){
  __shared__ __align__(16) char smem[13440];
  int b = blockIdx.x;
  int t = threadIdx.x;

  if (b < 1000) {
    // ---- adj -> bitmask: one u32 word per THREAD x2, 16 dwordx4 in flight ----
    int id = b * 256 + t;
    int w0 = id * 2;
    int n = w0 >> 6, c0 = w0 & 63;             // both words in same row (c0 even)
    int k0 = c0 * 32;
    const int* rowp = adj + n * Nk;
    u32 b0 = 0, b1 = 0;
    #pragma unroll
    for (int q = 0; q < 8; ++q) {
      int ka = min(k0 + q * 4, Nk - 4);
      int kb = min(k0 + 32 + q * 4, Nk - 4);
      i4 va = *(const i4*)(rowp + ka);
      i4 vb = *(const i4*)(rowp + kb);
      b0 |= (va[0] != 0 ? 1u : 0u) << (q * 4);
      b0 |= (va[1] != 0 ? 1u : 0u) << (q * 4 + 1);
      b0 |= (va[2] != 0 ? 1u : 0u) << (q * 4 + 2);
      b0 |= (va[3] != 0 ? 1u : 0u) << (q * 4 + 3);
      b1 |= (vb[0] != 0 ? 1u : 0u) << (q * 4);
      b1 |= (vb[1] != 0 ? 1u : 0u) << (q * 4 + 1);
      b1 |= (vb[2] != 0 ? 1u : 0u) << (q * 4 + 2);
      b1 |= (vb[3] != 0 ? 1u : 0u) << (q * 4 + 3);
    }
    int r0 = Nk - k0, r1 = Nk - k0 - 32;       // tail masks
    u32 t0 = (r0 >= 32) ? 0xFFFFFFFFu : ((r0 <= 0) ? 0u : ((1u << r0) - 1u));
    u32 t1 = (r1 >= 32) ? 0xFFFFFFFFu : ((r1 <= 0) ? 0u : ((1u << r1) - 1u));
    adjb[w0]     = b0 & t0;
    adjb[w0 + 1] = b1 & t1;
    return;
  }
  if (b < 1512) {
    // ---- h_dock (-> output 1), WhkB bf16 fragments, sk; h==1 blocks also WfT ----
    int idx = b - 1000;
    int kt = idx & 63, h = idx >> 6;
    float* hs   = (float*)smem;            // [32][65]
    float* part = (float*)(smem + 8320);   // [32][8]
    u16*   ts   = (u16*)(smem + 9344);     // [64 f][32 k]
    if (h == 1) {
      int id = kt * 256 + t;
      #pragma unroll
      for (int i = 0; i < 2; ++i) {
        int ix = id * 2 + i;               // ix = j*512 + k
        int j = ix >> 9, k = ix & 511;
        wfT[ix] = f2bf_rne(Wf[k * HD + j]);
      }
    }
    {
      int r = t >> 3, f0 = (t & 7) * 8;
      int gk = kt * 32 + r;
      float v[8];
      if (gk < Nk) {
        #pragma unroll
        for (int q = 0; q < 8; ++q) v[q] = bpk[f0 + q];
        for (int j = 0; j < FK; ++j) {
          float x = rdock[gk * FK + j];
          #pragma unroll
          for (int q = 0; q < 8; ++q) v[q] += x * Wpk[j * HD + f0 + q];
        }
        #pragma unroll
        for (int q = 0; q < 8; ++q) v[q] = elu1(v[q]);
        if (h == 0) {
          #pragma unroll
          for (int q = 0; q < 8; ++q) out_hdock[gk * HD + f0 + q] = v[q];
        }
      } else {
        #pragma unroll
        for (int q = 0; q < 8; ++q) v[q] = 0.f;
      }
      #pragma unroll
      for (int q = 0; q < 8; ++q) hs[r * 65 + f0 + q] = v[q];
    }
    __syncthreads();
    {
      int kl = t & 31, fq = t >> 5;
      float acc[8];
      #pragma unroll
      for (int j = 0; j < 8; ++j) acc[j] = 0.f;
      for (int d = 0; d < HD; ++d) {
        float hv = hs[kl * 65 + d];
        const float* wr = Wa + (h * HD + d) * HD + fq * 8;
        #pragma unroll
        for (int j = 0; j < 8; ++j) acc[j] += hv * wr[j];
      }
      float ps = 0.f;
      #pragma unroll
      for (int j = 0; j < 8; ++j) ps += acc[j] * a2[h * HD + fq * 8 + j];
      part[kl * 8 + fq] = ps;
      #pragma unroll
      for (int j = 0; j < 8; ++j)
        ts[(fq * 8 + j) * 32 + kl] = f2bf_rne(acc[j]);
    }
    __syncthreads();
    if (t < 32) {
      float s = 0.f;
      #pragma unroll
      for (int q = 0; q < 8; ++q) s += part[t * 8 + q];
      sk[h * KP + kt * 32 + t] = s * LOG2E;
    }
    {
      int cc = t >> 6, lane = t & 63, g = (t >> 4) & 3, c16 = t & 15;
      int f = cc * 16 + c16;
      u4v val = *(const u4v*)&ts[f * 32 + g * 8];
      *(u4v*)(whkB + (((h * NKB + kt) * 4 + cc) * 64 + lane) * 8) = val;
    }
    return;
  }
  {
    // ---- sd[h][n] = (elu(raw_drone@Wpd+bpd) . (Wa_h@a1_h)) * log2e ----
    int bid = b - 1512;
    float* wa1 = (float*)smem;             // [8][64]
    #pragma unroll
    for (int i = 0; i < 2; ++i) {
      int ix = t + i * 256;
      int h = ix >> 6, d = ix & 63;
      float s = 0.f;
      for (int f = 0; f < HD; ++f) s += Wa[(h * HD + d) * HD + f] * a1[h * HD + f];
      wa1[ix] = s;
    }
    __syncthreads();
    int r4 = t >> 6, d = t & 63;
    for (int rr = 0; rr < 4; ++rr) {
      int n = bid * 16 + r4 * 4 + rr;      // 500*16 = 8000 exact
      float acc = bpd[d];
      for (int j = 0; j < FD; ++j) acc += rdrone[n * FD + j] * Wpd[j * HD + d];
      float hd = elu1(acc);
      #pragma unroll
      for (int h = 0; h < NH; ++h) {
        float v = hd * wa1[h * HD + d];
        v += __shfl_xor(v, 1);  v += __shfl_xor(v, 2);  v += __shfl_xor(v, 4);
        v += __shfl_xor(v, 8);  v += __shfl_xor(v, 16); v += __shfl_xor(v, 32);
        if (d == 0) sd[h * Nd + n] = v * LOG2E;
      }
    }
  }
}

// ---------- main: masked softmax(leaky(sd+sk)) @ Whk via MFMA ----------
// BYTE-IDENTICAL to R12's k_attn (52.9 us proven): grid 1000 = 125 nt x 8 h,
// 64 rows/block, 16 rows/wave, LDS 2-slot B staging, exp2 P path.
__global__ __launch_bounds__(256) void k_attn(const float* __restrict__ sd,
                                              const float* __restrict__ sk,
                                              const u16* __restrict__ whkB,
                                              const u32* __restrict__ adjb,
                                              u16* __restrict__ hp){
  int bid = blockIdx.x;
  int h = bid & 7, nt = bid >> 3;
  int t = threadIdx.x;
  int w = t >> 6, lane = t & 63, g = lane >> 4, c16 = lane & 15;
  int r0 = nt * 64 + w * 16;
  __shared__ u16 bslot[2][2048];     // 2 x 4KB B tiles
  __shared__ u16 ldshp[64 * 64];

  int rowA = r0 + c16;               // always < 8000
  float sdv = sd[h * Nd + rowA];
  f4 acc[4], accd;
  accd = (f4){0.f, 0.f, 0.f, 0.f};
  #pragma unroll
  for (int cc = 0; cc < 4; ++cc) acc[cc] = (f4){0.f, 0.f, 0.f, 0.f};
  s16x8 onesf = (s16x8)(short)((c16 == 0) ? 0x3F80 : 0);

  const u16* bb = whkB + h * (NKB * 4 * 64 * 8);
  const float* skh = sk + h * KP;
  const u32* ap = adjb + rowA * 64;
  int soff = w * 512 + lane * 8;     // this thread's stage slot offset (u16)

  // prologue: slot0 <- tile0 (direct), stag <- tile1 (regs)
  *(u4v*)&bslot[0][soff] = *(const u4v*)(bb + soff);
  u4v stag = *(const u4v*)(bb + 2048 + soff);
  f4 cs0 = *(const f4*)(skh + g * 8);
  f4 cs1 = *(const f4*)(skh + g * 8 + 4);
  u4v caw = *(const u4v*)(ap);
  __syncthreads();

  for (int kb4 = 0; kb4 < 16; ++kb4) {
    u4v naw = *(const u4v*)(ap + kb4 * 4 + 4);  // kb4=15 overreads 16B in-ws
    #pragma unroll
    for (int u = 0; u < 4; ++u) {
      int kb = kb4 * 4 + u;
      // issue-early: B tile kb+2 (tail overreads stay inside ws) + next sk
      u4v nx = *(const u4v*)(bb + (kb + 2) * 2048 + soff);
      const float* nsp = skh + (kb + 1) * 32 + g * 8;
      f4 ns0 = *(const f4*)nsp;
      f4 ns1 = *(const f4*)(nsp + 4);

      u32 ab = (caw[u] >> (g * 8)) & 0xffu;
      union { s16x8 v; u32 d[4]; } af;
      {
        f4 x0 = cs0 + sdv;
        f4 x1 = cs1 + sdv;
        x0 = __builtin_elementwise_max(x0, x0 * NSLOPE);   // leaky (log2e pre-folded)
        x1 = __builtin_elementwise_max(x1, x1 * NSLOPE);
        float p[8];
        #pragma unroll
        for (int e = 0; e < 4; ++e) {
          p[e]     = __builtin_amdgcn_exp2f(x0[e]);
          p[e + 4] = __builtin_amdgcn_exp2f(x1[e]);
        }
        #pragma unroll
        for (int e = 0; e < 8; ++e) {
          int mk = __builtin_amdgcn_sbfe(ab, e, 1);        // 0 or -1
          p[e] = __uint_as_float(__float_as_uint(p[e]) & (u32)mk);
        }
        #pragma unroll
        for (int jj = 0; jj < 4; ++jj)
          asm("v_cvt_pk_bf16_f32 %0, %1, %2"
              : "=v"(af.d[jj]) : "v"(p[2 * jj]), "v"(p[2 * jj + 1]));
      }
      __syncthreads();                 // orders prev write->this read & read->overwrite
      *(u4v*)&bslot[(kb + 1) & 1][soff] = stag;            // write-late (kb=63: dead slot)
      s16x8 b0 = *(const s16x8*)&bslot[kb & 1][lane * 8];
      s16x8 b1 = *(const s16x8*)&bslot[kb & 1][512 + lane * 8];
      s16x8 b2 = *(const s16x8*)&bslot[kb & 1][1024 + lane * 8];
      s16x8 b3 = *(const s16x8*)&bslot[kb & 1][1536 + lane * 8];
      accd   = __builtin_amdgcn_mfma_f32_16x16x32_bf16(af.v, onesf, accd, 0, 0, 0);
      acc[0] = __builtin_amdgcn_mfma_f32_16x16x32_bf16(af.v, b0, acc[0], 0, 0, 0);
      acc[1] = __builtin_amdgcn_mfma_f32_16x16x32_bf16(af.v, b1, acc[1], 0, 0, 0);
      acc[2] = __builtin_amdgcn_mfma_f32_16x16x32_bf16(af.v, b2, acc[2], 0, 0, 0);
      acc[3] = __builtin_amdgcn_mfma_f32_16x16x32_bf16(af.v, b3, acc[3], 0, 0, 0);
      stag = nx;
      cs0 = ns0; cs1 = ns1;
    }
    caw = naw;
  }

  // epilogue: den for row g*4+j lives in lane g*16 reg j -> broadcast
  #pragma unroll
  for (int j = 0; j < 4; ++j) {
    float den = __shfl(accd[j], lane & 48);
    float linv = (den > 0.f) ? 1.f / den : 0.f;
    #pragma unroll
    for (int cc = 0; cc < 4; ++cc) {
      float o = acc[cc][j] * linv;
      ldshp[(w * 16 + g * 4 + j) * 64 + cc * 16 + c16] = f2bf_rne(elu1(o));
    }
  }
  __syncthreads();
  {
    int r = t >> 2, q = t & 3;           // 64 rows x 4 chunks of 16 u16
    int row = nt * 64 + r;
    u16* dst = hp + row * 512 + h * 64 + q * 16;
    const u16* src = ldshp + r * 64 + q * 16;
    *(u4v*)(dst)     = *(const u4v*)(src);
    *(u4v*)(dst + 8) = *(const u4v*)(src + 8);
  }
}

// ---------- epilogue: out_drone = hp @ Wf + bf; wave = 16 rows x 16 cols ----------
__global__ __launch_bounds__(256) void k_out(const u16* __restrict__ hp,
                                             const u16* __restrict__ wfT,
                                             const float* __restrict__ bfv,
                                             float* __restrict__ out){
  int t = threadIdx.x;
  int w = t >> 6, lane = t & 63, g = lane >> 4, c16 = lane & 15;
  int r0 = blockIdx.x * 16;  // grid 500 -> 8000 exact
  f4 acc = (f4){0.f, 0.f, 0.f, 0.f};
  const u16* ap = hp + (r0 + c16) * 512 + g * 8;
  const u16* bp = wfT + (w * 16 + c16) * 512 + g * 8;
  #pragma unroll 4
  for (int kb = 0; kb < 16; ++kb) {
    s16x8 a = *(const s16x8*)(ap + kb * 32);
    s16x8 b = *(const s16x8*)(bp + kb * 32);
    acc = __builtin_amdgcn_mfma_f32_16x16x32_bf16(a, b, acc, 0, 0, 0);
  }
  float bias = bfv[w * 16 + c16];
  #pragma unroll
  for (int j = 0; j < 4; ++j)
    out[(r0 + g * 4 + j) * HD + w * 16 + c16] = acc[j] + bias;
}

extern "C" void kernel_launch(void* const* d_in, const int* in_sizes, int n_in,
                              void* d_out, int out_size, void* d_ws, size_t ws_size,
                              hipStream_t stream) {
  const float* raw_drone = (const float*)d_in[0];
  const float* raw_dock  = (const float*)d_in[1];
  const int*   adj       = (const int*)d_in[2];
  const float* Wpd = (const float*)d_in[3];
  const float* bpd = (const float*)d_in[4];
  const float* Wpk = (const float*)d_in[5];
  const float* bpk = (const float*)d_in[6];
  const float* Wa  = (const float*)d_in[7];
  const float* a1  = (const float*)d_in[8];
  const float* a2  = (const float*)d_in[9];
  const float* Wf  = (const float*)d_in[10];
  const float* bfb = (const float*)d_in[11];
  float* out = (float*)d_out;
  float* out_hdock = out + Nd * HD;

  char* ws = (char*)d_ws;
  u16*   whkB = (u16*)(ws + WS_WHKB);
  float* skv  = (float*)(ws + WS_SK);
  float* sdv  = (float*)(ws + WS_SD);
  u32*   adjb = (u32*)(ws + WS_ADJB);
  u16*   wfT  = (u16*)(ws + WS_WFT);
  u16*   hp   = (u16*)(ws + WS_HP);

  k_prep<<<2012, 256, 0, stream>>>(raw_drone, raw_dock, adj, Wpd, bpd, Wpk, bpk,
                                   Wa, a1, a2, Wf, out_hdock, whkB, skv, sdv,
                                   adjb, wfT);
  k_attn<<<1000, 256, 0, stream>>>(sdv, skv, whkB, adjb, hp);
  k_out <<<500, 256, 0, stream>>>(hp, wfT, bfb, out);
}

// Round 16
// 99.278 us; speedup vs baseline: 1.1625x; 1.0776x over previous
//
#include <hip/hip_runtime.h>
#include <stdint.h>

#define Nd 8000
#define Nk 2000
#define FD 32
#define FK 16
#define HD 64
#define NH 8
#define KP 2048
#define NKB 64   // KP/32
#define LOG2E 1.44269504088896f
#define NSLOPE 0.2f

typedef float f4 __attribute__((ext_vector_type(4)));
typedef short s16x8 __attribute__((ext_vector_type(8)));
typedef int i4 __attribute__((ext_vector_type(4)));
typedef unsigned int u32;
typedef unsigned short u16;
typedef unsigned int u4v __attribute__((ext_vector_type(4)));

// ---- workspace layout (bytes), 16B aligned; total ~12.7 MB ----
#define WS_WHKB   0          // bf16 [8][64 kb][4 cc][64 lane][8 e] = 2 MB
#define WS_SK     2097152    // f32 [8][2048] (pre-scaled by log2e)
#define WS_SD     2162688    // f32 [8][8000] (pre-scaled by log2e)
#define WS_ADJB   2418688    // u32 [8000][64] bitmask (bit = k%32, word = k/32)
#define WS_WFT    4466688    // bf16 [64 j][512 k]
#define WS_HP     4532224    // bf16 [8000][512]

__device__ inline u16 f2bf_rne(float f){
  u32 u = __float_as_uint(f);
  u32 r = u + 0x7fffu + ((u >> 16) & 1u);
  return (u16)(r >> 16);
}
__device__ inline float elu1(float x){
  return x > 0.f ? x : (__builtin_amdgcn_exp2f(x * LOG2E) - 1.f);
}

// ---------- fused prep: [0,2000) adjb | [2000,2512) whk(+hdock,wfT) | [2512,3012) dsd ----------
// All phases rewritten for memory-level parallelism + f4 coalescing (R15 was
// latency-serialized: VALUBusy 8%, HBM 9%).
__global__ __launch_bounds__(256) void k_prep(const float* __restrict__ rdrone,
                                              const float* __restrict__ rdock,
                                              const int*   __restrict__ adj,
                                              const float* __restrict__ Wpd,
                                              const float* __restrict__ bpd,
                                              const float* __restrict__ Wpk,
                                              const float* __restrict__ bpk,
                                              const float* __restrict__ Wa,
                                              const float* __restrict__ a1,
                                              const float* __restrict__ a2,
                                              const float* __restrict__ Wf,
                                              float* __restrict__ out_hdock,
                                              u16* __restrict__ whkB,
                                              float* __restrict__ sk,
                                              float* __restrict__ sd,
                                              u32* __restrict__ adjb,
                                              u16* __restrict__ wfT){
  __shared__ __align__(16) char smem[13440];
  int b = blockIdx.x;
  int t = threadIdx.x;

  if (b < 2000) {
    // ---- adj -> bitmask: ONE u32 word per thread; 8 i4 loads all in flight ----
    int W = b * 256 + t;                 // 2000*256 = 512000 = 8000*64 exact
    int n = W >> 6, c = W & 63;
    int k0 = c * 32;
    const int* rowp = adj + n * Nk;
    u32 bits = 0;
    #pragma unroll
    for (int q = 0; q < 8; ++q) {
      int kq = min(k0 + q * 4, Nk - 4);  // clamped in-bounds load
      i4 v = *(const i4*)(rowp + kq);
      bits |= (v[0] != 0 ? 1u : 0u) << (q * 4);
      bits |= (v[1] != 0 ? 1u : 0u) << (q * 4 + 1);
      bits |= (v[2] != 0 ? 1u : 0u) << (q * 4 + 2);
      bits |= (v[3] != 0 ? 1u : 0u) << (q * 4 + 3);
    }
    int rem = Nk - k0;                   // tail mask kills clamped/pad bits
    u32 tm = (rem >= 32) ? 0xFFFFFFFFu : ((rem <= 0) ? 0u : ((1u << rem) - 1u));
    adjb[W] = bits & tm;
    return;
  }
  if (b < 2512) {
    // ---- h_dock (-> output 1), WhkB bf16 fragments, sk; h==1 blocks also WfT ----
    int idx = b - 2000;
    int kt = idx & 63, h = idx >> 6;
    float* hs   = (float*)smem;            // [32][65]
    float* part = (float*)(smem + 8320);   // [32][8]
    u16*   ts   = (u16*)(smem + 9344);     // [64 f][32 k]
    if (h == 1) {
      int id = kt * 256 + t;
      #pragma unroll
      for (int i = 0; i < 2; ++i) {
        int ix = id * 2 + i;               // ix = j*512 + k
        int j = ix >> 9, k = ix & 511;
        wfT[ix] = f2bf_rne(Wf[k * HD + j]);
      }
    }
    {
      int r = t >> 3, f0 = (t & 7) * 8;
      int gk = kt * 32 + r;
      float v[8];
      if (gk < Nk) {
        const f4* rr = (const f4*)(rdock + gk * FK);   // 16 floats, 64B aligned
        f4 y0 = rr[0], y1 = rr[1], y2 = rr[2], y3 = rr[3];
        float xr[16] = {y0[0],y0[1],y0[2],y0[3], y1[0],y1[1],y1[2],y1[3],
                        y2[0],y2[1],y2[2],y2[3], y3[0],y3[1],y3[2],y3[3]};
        const f4* bq = (const f4*)(bpk + f0);
        f4 b0 = bq[0], b1 = bq[1];
        v[0]=b0[0]; v[1]=b0[1]; v[2]=b0[2]; v[3]=b0[3];
        v[4]=b1[0]; v[5]=b1[1]; v[6]=b1[2]; v[7]=b1[3];
        #pragma unroll
        for (int j = 0; j < FK; ++j) {
          const f4* wp = (const f4*)(Wpk + j * HD + f0);
          f4 w0 = wp[0], w1 = wp[1];
          float x = xr[j];
          v[0] += x*w0[0]; v[1] += x*w0[1]; v[2] += x*w0[2]; v[3] += x*w0[3];
          v[4] += x*w1[0]; v[5] += x*w1[1]; v[6] += x*w1[2]; v[7] += x*w1[3];
        }
        #pragma unroll
        for (int q = 0; q < 8; ++q) v[q] = elu1(v[q]);
        if (h == 0) {
          #pragma unroll
          for (int q = 0; q < 8; ++q) out_hdock[gk * HD + f0 + q] = v[q];
        }
      } else {
        #pragma unroll
        for (int q = 0; q < 8; ++q) v[q] = 0.f;
      }
      #pragma unroll
      for (int q = 0; q < 8; ++q) hs[r * 65 + f0 + q] = v[q];
    }
    __syncthreads();
    {
      int kl = t & 31, fq = t >> 5;
      const f4* war = (const f4*)(Wa + h * HD * HD);   // head panel, f4 units
      float acc[8];
      #pragma unroll
      for (int j = 0; j < 8; ++j) acc[j] = 0.f;
      #pragma unroll 4
      for (int d = 0; d < HD; ++d) {
        float hv = hs[kl * 65 + d];
        f4 wA = war[d * 16 + fq * 2];
        f4 wB = war[d * 16 + fq * 2 + 1];
        acc[0] += hv * wA[0]; acc[1] += hv * wA[1];
        acc[2] += hv * wA[2]; acc[3] += hv * wA[3];
        acc[4] += hv * wB[0]; acc[5] += hv * wB[1];
        acc[6] += hv * wB[2]; acc[7] += hv * wB[3];
      }
      float ps = 0.f;
      #pragma unroll
      for (int j = 0; j < 8; ++j) ps += acc[j] * a2[h * HD + fq * 8 + j];
      part[kl * 8 + fq] = ps;
      #pragma unroll
      for (int j = 0; j < 8; ++j)
        ts[(fq * 8 + j) * 32 + kl] = f2bf_rne(acc[j]);
    }
    __syncthreads();
    if (t < 32) {
      float s = 0.f;
      #pragma unroll
      for (int q = 0; q < 8; ++q) s += part[t * 8 + q];
      sk[h * KP + kt * 32 + t] = s * LOG2E;
    }
    {
      int cc = t >> 6, lane = t & 63, g = (t >> 4) & 3, c16 = t & 15;
      int f = cc * 16 + c16;
      u4v val = *(const u4v*)&ts[f * 32 + g * 8];
      *(u4v*)(whkB + (((h * NKB + kt) * 4 + cc) * 64 + lane) * 8) = val;
    }
    return;
  }
  {
    // ---- sd[h][n] = (elu(raw_drone@Wpd+bpd) . (Wa_h@a1_h)) * log2e ----
    int bid = b - 2512;
    float* wa1 = (float*)smem;             // [8][64] = 512 floats
    // parallel wa1: 8 lanes per entry, coalesced 32B slices, depth 8 not 64
    #pragma unroll
    for (int pass = 0; pass < 16; ++pass) {
      int ix = pass * 32 + (t >> 3);       // entry = h*64+d, 32 entries/pass
      int fs = (t & 7) * 8;
      const f4* wr = (const f4*)(Wa + ix * HD + fs);
      const f4* ar = (const f4*)(a1 + (ix >> 6) * HD + fs);
      f4 wv0 = wr[0], wv1 = wr[1];
      f4 av0 = ar[0], av1 = ar[1];
      float s = (wv0[0]*av0[0] + wv0[1]*av0[1]) + (wv0[2]*av0[2] + wv0[3]*av0[3])
              + (wv1[0]*av1[0] + wv1[1]*av1[1]) + (wv1[2]*av1[2] + wv1[3]*av1[3]);
      s += __shfl_xor(s, 1); s += __shfl_xor(s, 2); s += __shfl_xor(s, 4);
      if ((t & 7) == 0) wa1[ix] = s;
    }
    __syncthreads();
    int r4 = t >> 6, d = t & 63;
    for (int rr = 0; rr < 4; ++rr) {
      int n = bid * 16 + r4 * 4 + rr;      // 500*16 = 8000 exact
      const f4* rp = (const f4*)(rdrone + n * FD);   // 32 floats, 8 f4
      float xr[FD];
      #pragma unroll
      for (int q = 0; q < 8; ++q) {
        f4 xv = rp[q];
        xr[q*4+0] = xv[0]; xr[q*4+1] = xv[1]; xr[q*4+2] = xv[2]; xr[q*4+3] = xv[3];
      }
      float a0 = bpd[d], a1s = 0.f, a2s = 0.f, a3s = 0.f;
      #pragma unroll
      for (int j = 0; j < FD; j += 4) {    // 4 independent chains, coalesced Wpd
        a0  += xr[j]   * Wpd[j * HD + d];
        a1s += xr[j+1] * Wpd[(j+1) * HD + d];
        a2s += xr[j+2] * Wpd[(j+2) * HD + d];
        a3s += xr[j+3] * Wpd[(j+3) * HD + d];
      }
      float hd = elu1((a0 + a1s) + (a2s + a3s));
      #pragma unroll
      for (int h = 0; h < NH; ++h) {
        float v = hd * wa1[h * HD + d];
        v += __shfl_xor(v, 1);  v += __shfl_xor(v, 2);  v += __shfl_xor(v, 4);
        v += __shfl_xor(v, 8);  v += __shfl_xor(v, 16); v += __shfl_xor(v, 32);
        if (d == 0) sd[h * Nd + n] = v * LOG2E;
      }
    }
  }
}

// ---------- main: masked softmax(leaky(sd+sk)) @ Whk via MFMA ----------
// BYTE-IDENTICAL to R12/R15 k_attn (proven): grid 1000 = 125 nt x 8 h,
// 64 rows/block, 16 rows/wave, LDS 2-slot B staging, exp2 P path.
__global__ __launch_bounds__(256) void k_attn(const float* __restrict__ sd,
                                              const float* __restrict__ sk,
                                              const u16* __restrict__ whkB,
                                              const u32* __restrict__ adjb,
                                              u16* __restrict__ hp){
  int bid = blockIdx.x;
  int h = bid & 7, nt = bid >> 3;
  int t = threadIdx.x;
  int w = t >> 6, lane = t & 63, g = lane >> 4, c16 = lane & 15;
  int r0 = nt * 64 + w * 16;
  __shared__ u16 bslot[2][2048];     // 2 x 4KB B tiles
  __shared__ u16 ldshp[64 * 64];

  int rowA = r0 + c16;               // always < 8000
  float sdv = sd[h * Nd + rowA];
  f4 acc[4], accd;
  accd = (f4){0.f, 0.f, 0.f, 0.f};
  #pragma unroll
  for (int cc = 0; cc < 4; ++cc) acc[cc] = (f4){0.f, 0.f, 0.f, 0.f};
  s16x8 onesf = (s16x8)(short)((c16 == 0) ? 0x3F80 : 0);

  const u16* bb = whkB + h * (NKB * 4 * 64 * 8);
  const float* skh = sk + h * KP;
  const u32* ap = adjb + rowA * 64;
  int soff = w * 512 + lane * 8;     // this thread's stage slot offset (u16)

  // prologue: slot0 <- tile0 (direct), stag <- tile1 (regs)
  *(u4v*)&bslot[0][soff] = *(const u4v*)(bb + soff);
  u4v stag = *(const u4v*)(bb + 2048 + soff);
  f4 cs0 = *(const f4*)(skh + g * 8);
  f4 cs1 = *(const f4*)(skh + g * 8 + 4);
  u4v caw = *(const u4v*)(ap);
  __syncthreads();

  for (int kb4 = 0; kb4 < 16; ++kb4) {
    u4v naw = *(const u4v*)(ap + kb4 * 4 + 4);  // kb4=15 overreads 16B in-ws
    #pragma unroll
    for (int u = 0; u < 4; ++u) {
      int kb = kb4 * 4 + u;
      // issue-early: B tile kb+2 (tail overreads stay inside ws) + next sk
      u4v nx = *(const u4v*)(bb + (kb + 2) * 2048 + soff);
      const float* nsp = skh + (kb + 1) * 32 + g * 8;
      f4 ns0 = *(const f4*)nsp;
      f4 ns1 = *(const f4*)(nsp + 4);

      u32 ab = (caw[u] >> (g * 8)) & 0xffu;
      union { s16x8 v; u32 d[4]; } af;
      {
        f4 x0 = cs0 + sdv;
        f4 x1 = cs1 + sdv;
        x0 = __builtin_elementwise_max(x0, x0 * NSLOPE);   // leaky (log2e pre-folded)
        x1 = __builtin_elementwise_max(x1, x1 * NSLOPE);
        float p[8];
        #pragma unroll
        for (int e = 0; e < 4; ++e) {
          p[e]     = __builtin_amdgcn_exp2f(x0[e]);
          p[e + 4] = __builtin_amdgcn_exp2f(x1[e]);
        }
        #pragma unroll
        for (int e = 0; e < 8; ++e) {
          int mk = __builtin_amdgcn_sbfe(ab, e, 1);        // 0 or -1
          p[e] = __uint_as_float(__float_as_uint(p[e]) & (u32)mk);
        }
        #pragma unroll
        for (int jj = 0; jj < 4; ++jj)
          asm("v_cvt_pk_bf16_f32 %0, %1, %2"
              : "=v"(af.d[jj]) : "v"(p[2 * jj]), "v"(p[2 * jj + 1]));
      }
      __syncthreads();                 // orders prev write->this read & read->overwrite
      *(u4v*)&bslot[(kb + 1) & 1][soff] = stag;            // write-late (kb=63: dead slot)
      s16x8 b0 = *(const s16x8*)&bslot[kb & 1][lane * 8];
      s16x8 b1 = *(const s16x8*)&bslot[kb & 1][512 + lane * 8];
      s16x8 b2 = *(const s16x8*)&bslot[kb & 1][1024 + lane * 8];
      s16x8 b3 = *(const s16x8*)&bslot[kb & 1][1536 + lane * 8];
      accd   = __builtin_amdgcn_mfma_f32_16x16x32_bf16(af.v, onesf, accd, 0, 0, 0);
      acc[0] = __builtin_amdgcn_mfma_f32_16x16x32_bf16(af.v, b0, acc[0], 0, 0, 0);
      acc[1] = __builtin_amdgcn_mfma_f32_16x16x32_bf16(af.v, b1, acc[1], 0, 0, 0);
      acc[2] = __builtin_amdgcn_mfma_f32_16x16x32_bf16(af.v, b2, acc[2], 0, 0, 0);
      acc[3] = __builtin_amdgcn_mfma_f32_16x16x32_bf16(af.v, b3, acc[3], 0, 0, 0);
      stag = nx;
      cs0 = ns0; cs1 = ns1;
    }
    caw = naw;
  }

  // epilogue: den for row g*4+j lives in lane g*16 reg j -> broadcast
  #pragma unroll
  for (int j = 0; j < 4; ++j) {
    float den = __shfl(accd[j], lane & 48);
    float linv = (den > 0.f) ? 1.f / den : 0.f;
    #pragma unroll
    for (int cc = 0; cc < 4; ++cc) {
      float o = acc[cc][j] * linv;
      ldshp[(w * 16 + g * 4 + j) * 64 + cc * 16 + c16] = f2bf_rne(elu1(o));
    }
  }
  __syncthreads();
  {
    int r = t >> 2, q = t & 3;           // 64 rows x 4 chunks of 16 u16
    int row = nt * 64 + r;
    u16* dst = hp + row * 512 + h * 64 + q * 16;
    const u16* src = ldshp + r * 64 + q * 16;
    *(u4v*)(dst)     = *(const u4v*)(src);
    *(u4v*)(dst + 8) = *(const u4v*)(src + 8);
  }
}

// ---------- epilogue: out_drone = hp @ Wf + bf; wave = 16 rows x 16 cols ----------
__global__ __launch_bounds__(256) void k_out(const u16* __restrict__ hp,
                                             const u16* __restrict__ wfT,
                                             const float* __restrict__ bfv,
                                             float* __restrict__ out){
  int t = threadIdx.x;
  int w = t >> 6, lane = t & 63, g = lane >> 4, c16 = lane & 15;
  int r0 = blockIdx.x * 16;  // grid 500 -> 8000 exact
  f4 acc = (f4){0.f, 0.f, 0.f, 0.f};
  const u16* ap = hp + (r0 + c16) * 512 + g * 8;
  const u16* bp = wfT + (w * 16 + c16) * 512 + g * 8;
  #pragma unroll 4
  for (int kb = 0; kb < 16; ++kb) {
    s16x8 a = *(const s16x8*)(ap + kb * 32);
    s16x8 b = *(const s16x8*)(bp + kb * 32);
    acc = __builtin_amdgcn_mfma_f32_16x16x32_bf16(a, b, acc, 0, 0, 0);
  }
  float bias = bfv[w * 16 + c16];
  #pragma unroll
  for (int j = 0; j < 4; ++j)
    out[(r0 + g * 4 + j) * HD + w * 16 + c16] = acc[j] + bias;
}

extern "C" void kernel_launch(void* const* d_in, const int* in_sizes, int n_in,
                              void* d_out, int out_size, void* d_ws, size_t ws_size,
                              hipStream_t stream) {
  const float* raw_drone = (const float*)d_in[0];
  const float* raw_dock  = (const float*)d_in[1];
  const int*   adj       = (const int*)d_in[2];
  const float* Wpd = (const float*)d_in[3];
  const float* bpd = (const float*)d_in[4];
  const float* Wpk = (const float*)d_in[5];
  const float* bpk = (const float*)d_in[6];
  const float* Wa  = (const float*)d_in[7];
  const float* a1  = (const float*)d_in[8];
  const float* a2  = (const float*)d_in[9];
  const float* Wf  = (const float*)d_in[10];
  const float* bfb = (const float*)d_in[11];
  float* out = (float*)d_out;
  float* out_hdock = out + Nd * HD;

  char* ws = (char*)d_ws;
  u16*   whkB = (u16*)(ws + WS_WHKB);
  float* skv  = (float*)(ws + WS_SK);
  float* sdv  = (float*)(ws + WS_SD);
  u32*   adjb = (u32*)(ws + WS_ADJB);
  u16*   wfT  = (u16*)(ws + WS_WFT);
  u16*   hp   = (u16*)(ws + WS_HP);

  k_prep<<<3012, 256, 0, stream>>>(raw_drone, raw_dock, adj, Wpd, bpd, Wpk, bpk,
                                   Wa, a1, a2, Wf, out_hdock, whkB, skv, sdv,
                                   adjb, wfT);
  k_attn<<<1000, 256, 0, stream>>>(sdv, skv, whkB, adjb, hp);
  k_out <<<500, 256, 0, stream>>>(hp, wfT, bfb, out);
}

// Round 18
// 98.842 us; speedup vs baseline: 1.1677x; 1.0044x over previous
//
#include <hip/hip_runtime.h>
#include <stdint.h>

#define Nd 8000
#define Nk 2000
#define FD 32
#define FK 16
#define HD 64
#define NH 8
#define KP 2048
#define NKB 64   // KP/32
#define LOG2E 1.44269504088896f
#define NSLOPE 0.2f

typedef float f4 __attribute__((ext_vector_type(4)));
typedef short s16x8 __attribute__((ext_vector_type(8)));
typedef int i4 __attribute__((ext_vector_type(4)));
typedef unsigned int u32;
typedef unsigned short u16;
typedef unsigned int u4v __attribute__((ext_vector_type(4)));

// ---- workspace layout (bytes), 16B aligned; total ~12.7 MB ----
#define WS_WHKB   0          // bf16 [8][64 kb][4 cc][64 lane][8 e] = 2 MB
#define WS_SK     2097152    // f32 [8][2048] (pre-scaled by log2e)
#define WS_SD     2162688    // f32 [8][8000] (pre-scaled by log2e)
#define WS_ADJB   2418688    // u32 [8000][64] bitmask (bit = k%32, word = k/32)
#define WS_WFT    4466688    // bf16 [64 j][512 k]
#define WS_HP     4532224    // bf16 [8000][512]

__device__ inline u16 f2bf_rne(float f){
  u32 u = __float_as_uint(f);
  u32 r = u + 0x7fffu + ((u >> 16) & 1u);
  return (u16)(r >> 16);
}
__device__ inline float elu1(float x){
  return x > 0.f ? x : (__builtin_amdgcn_exp2f(x * LOG2E) - 1.f);
}

// ---------- fused prep: [0,2000) adjb | [2000,2512) whk(+hdock,wfT) | [2512,3012) dsd ----------
__global__ __launch_bounds__(256) void k_prep(const float* __restrict__ rdrone,
                                              const float* __restrict__ rdock,
                                              const int*   __restrict__ adj,
                                              const float* __restrict__ Wpd,
                                              const float* __restrict__ bpd,
                                              const float* __restrict__ Wpk,
                                              const float* __restrict__ bpk,
                                              const float* __restrict__ Wa,
                                              const float* __restrict__ a1,
                                              const float* __restrict__ a2,
                                              const float* __restrict__ Wf,
                                              float* __restrict__ out_hdock,
                                              u16* __restrict__ whkB,
                                              float* __restrict__ sk,
                                              float* __restrict__ sd,
                                              u32* __restrict__ adjb,
                                              u16* __restrict__ wfT){
  __shared__ __align__(16) char smem[13440];
  int b = blockIdx.x;
  int t = threadIdx.x;

  if (b < 2000) {
    // ---- adj -> bitmask: ONE u32 word per thread; 8 i4 loads all in flight ----
    int W = b * 256 + t;                 // 2000*256 = 512000 = 8000*64 exact
    int n = W >> 6, c = W & 63;
    int k0 = c * 32;
    const int* rowp = adj + n * Nk;
    u32 bits = 0;
    #pragma unroll
    for (int q = 0; q < 8; ++q) {
      int kq = min(k0 + q * 4, Nk - 4);  // clamped in-bounds load
      i4 v = *(const i4*)(rowp + kq);
      bits |= (v[0] != 0 ? 1u : 0u) << (q * 4);
      bits |= (v[1] != 0 ? 1u : 0u) << (q * 4 + 1);
      bits |= (v[2] != 0 ? 1u : 0u) << (q * 4 + 2);
      bits |= (v[3] != 0 ? 1u : 0u) << (q * 4 + 3);
    }
    int rem = Nk - k0;                   // tail mask kills clamped/pad bits
    u32 tm = (rem >= 32) ? 0xFFFFFFFFu : ((rem <= 0) ? 0u : ((1u << rem) - 1u));
    adjb[W] = bits & tm;
    return;
  }
  if (b < 2512) {
    // ---- h_dock (-> output 1), WhkB bf16 fragments, sk; h==1 blocks also WfT ----
    int idx = b - 2000;
    int kt = idx & 63, h = idx >> 6;
    float* hs   = (float*)smem;            // [32][65]
    float* part = (float*)(smem + 8320);   // [32][8]
    u16*   ts   = (u16*)(smem + 9344);     // [64 f][32 k]
    if (h == 1) {
      int id = kt * 256 + t;
      #pragma unroll
      for (int i = 0; i < 2; ++i) {
        int ix = id * 2 + i;               // ix = j*512 + k
        int j = ix >> 9, k = ix & 511;
        wfT[ix] = f2bf_rne(Wf[k * HD + j]);
      }
    }
    {
      int r = t >> 3, f0 = (t & 7) * 8;
      int gk = kt * 32 + r;
      float v[8];
      if (gk < Nk) {
        const f4* rr = (const f4*)(rdock + gk * FK);   // 16 floats, 64B aligned
        f4 y0 = rr[0], y1 = rr[1], y2 = rr[2], y3 = rr[3];
        float xr[16] = {y0[0],y0[1],y0[2],y0[3], y1[0],y1[1],y1[2],y1[3],
                        y2[0],y2[1],y2[2],y2[3], y3[0],y3[1],y3[2],y3[3]};
        const f4* bq = (const f4*)(bpk + f0);
        f4 b0 = bq[0], b1 = bq[1];
        v[0]=b0[0]; v[1]=b0[1]; v[2]=b0[2]; v[3]=b0[3];
        v[4]=b1[0]; v[5]=b1[1]; v[6]=b1[2]; v[7]=b1[3];
        #pragma unroll
        for (int j = 0; j < FK; ++j) {
          const f4* wp = (const f4*)(Wpk + j * HD + f0);
          f4 w0 = wp[0], w1 = wp[1];
          float x = xr[j];
          v[0] += x*w0[0]; v[1] += x*w0[1]; v[2] += x*w0[2]; v[3] += x*w0[3];
          v[4] += x*w1[0]; v[5] += x*w1[1]; v[6] += x*w1[2]; v[7] += x*w1[3];
        }
        #pragma unroll
        for (int q = 0; q < 8; ++q) v[q] = elu1(v[q]);
        if (h == 0) {
          #pragma unroll
          for (int q = 0; q < 8; ++q) out_hdock[gk * HD + f0 + q] = v[q];
        }
      } else {
        #pragma unroll
        for (int q = 0; q < 8; ++q) v[q] = 0.f;
      }
      #pragma unroll
      for (int q = 0; q < 8; ++q) hs[r * 65 + f0 + q] = v[q];
    }
    __syncthreads();
    {
      int kl = t & 31, fq = t >> 5;
      const f4* war = (const f4*)(Wa + h * HD * HD);   // head panel, f4 units
      float acc[8];
      #pragma unroll
      for (int j = 0; j < 8; ++j) acc[j] = 0.f;
      #pragma unroll 4
      for (int d = 0; d < HD; ++d) {
        float hv = hs[kl * 65 + d];
        f4 wA = war[d * 16 + fq * 2];
        f4 wB = war[d * 16 + fq * 2 + 1];
        acc[0] += hv * wA[0]; acc[1] += hv * wA[1];
        acc[2] += hv * wA[2]; acc[3] += hv * wA[3];
        acc[4] += hv * wB[0]; acc[5] += hv * wB[1];
        acc[6] += hv * wB[2]; acc[7] += hv * wB[3];
      }
      float ps = 0.f;
      #pragma unroll
      for (int j = 0; j < 8; ++j) ps += acc[j] * a2[h * HD + fq * 8 + j];
      part[kl * 8 + fq] = ps;
      #pragma unroll
      for (int j = 0; j < 8; ++j)
        ts[(fq * 8 + j) * 32 + kl] = f2bf_rne(acc[j]);
    }
    __syncthreads();
    if (t < 32) {
      float s = 0.f;
      #pragma unroll
      for (int q = 0; q < 8; ++q) s += part[t * 8 + q];
      sk[h * KP + kt * 32 + t] = s * LOG2E;
    }
    {
      int cc = t >> 6, lane = t & 63, g = (t >> 4) & 3, c16 = t & 15;
      int f = cc * 16 + c16;
      u4v val = *(const u4v*)&ts[f * 32 + g * 8];
      *(u4v*)(whkB + (((h * NKB + kt) * 4 + cc) * 64 + lane) * 8) = val;
    }
    return;
  }
  {
    // ---- sd[h][n] = (elu(raw_drone@Wpd+bpd) . (Wa_h@a1_h)) * log2e ----
    int bid = b - 2512;
    float* wa1 = (float*)smem;             // [8][64] = 512 floats
    // parallel wa1: 8 lanes per entry, coalesced 32B slices, depth 8 not 64
    #pragma unroll
    for (int pass = 0; pass < 16; ++pass) {
      int ix = pass * 32 + (t >> 3);       // entry = h*64+d, 32 entries/pass
      int fs = (t & 7) * 8;
      const f4* wr = (const f4*)(Wa + ix * HD + fs);
      const f4* ar = (const f4*)(a1 + (ix >> 6) * HD + fs);
      f4 wv0 = wr[0], wv1 = wr[1];
      f4 av0 = ar[0], av1 = ar[1];
      float s = (wv0[0]*av0[0] + wv0[1]*av0[1]) + (wv0[2]*av0[2] + wv0[3]*av0[3])
              + (wv1[0]*av1[0] + wv1[1]*av1[1]) + (wv1[2]*av1[2] + wv1[3]*av1[3]);
      s += __shfl_xor(s, 1); s += __shfl_xor(s, 2); s += __shfl_xor(s, 4);
      if ((t & 7) == 0) wa1[ix] = s;
    }
    __syncthreads();
    int r4 = t >> 6, d = t & 63;
    for (int rr = 0; rr < 4; ++rr) {
      int n = bid * 16 + r4 * 4 + rr;      // 500*16 = 8000 exact
      const f4* rp = (const f4*)(rdrone + n * FD);   // 32 floats, 8 f4
      float xr[FD];
      #pragma unroll
      for (int q = 0; q < 8; ++q) {
        f4 xv = rp[q];
        xr[q*4+0] = xv[0]; xr[q*4+1] = xv[1]; xr[q*4+2] = xv[2]; xr[q*4+3] = xv[3];
      }
      float a0 = bpd[d], a1s = 0.f, a2s = 0.f, a3s = 0.f;
      #pragma unroll
      for (int j = 0; j < FD; j += 4) {    // 4 independent chains, coalesced Wpd
        a0  += xr[j]   * Wpd[j * HD + d];
        a1s += xr[j+1] * Wpd[(j+1) * HD + d];
        a2s += xr[j+2] * Wpd[(j+2) * HD + d];
        a3s += xr[j+3] * Wpd[(j+3) * HD + d];
      }
      float hd = elu1((a0 + a1s) + (a2s + a3s));
      #pragma unroll
      for (int h = 0; h < NH; ++h) {
        float v = hd * wa1[h * HD + d];
        v += __shfl_xor(v, 1);  v += __shfl_xor(v, 2);  v += __shfl_xor(v, 4);
        v += __shfl_xor(v, 8);  v += __shfl_xor(v, 16); v += __shfl_xor(v, 32);
        if (d == 0) sd[h * Nd + n] = v * LOG2E;
      }
    }
  }
}

// ---------- main: masked softmax(leaky(sd+sk)) @ Whk via MFMA ----------
// grid 1000 = 125 nt x 8 h (h = bid&7 pins head to XCD). Block = 64 rows,
// wave w = 16 rows, LDS 2-slot B staging (issue-early/write-late), exp2 P.
__global__ __launch_bounds__(256) void k_attn(const float* __restrict__ sd,
                                              const float* __restrict__ sk,
                                              const u16* __restrict__ whkB,
                                              const u32* __restrict__ adjb,
                                              u16* __restrict__ hp){
  int bid = blockIdx.x;
  int h = bid & 7, nt = bid >> 3;
  int t = threadIdx.x;
  int w = t >> 6, lane = t & 63, g = lane >> 4, c16 = lane & 15;
  int r0 = nt * 64 + w * 16;
  __shared__ u16 bslot[2][2048];     // 2 x 4KB B tiles
  __shared__ u16 ldshp[64 * 64];

  int rowA = r0 + c16;               // always < 8000
  float sdv = sd[h * Nd + rowA];
  f4 acc[4], accd;
  accd = (f4){0.f, 0.f, 0.f, 0.f};
  #pragma unroll
  for (int cc = 0; cc < 4; ++cc) acc[cc] = (f4){0.f, 0.f, 0.f, 0.f};
  s16x8 onesf = (s16x8)(short)((c16 == 0) ? 0x3F80 : 0);

  const u16* bb = whkB + h * (NKB * 4 * 64 * 8);
  const float* skh = sk + h * KP;
  const u32* ap = adjb + rowA * 64;
  int soff = w * 512 + lane * 8;     // this thread's stage slot offset (u16)

  // prologue: slot0 <- tile0 (direct), stag <- tile1 (regs)
  *(u4v*)&bslot[0][soff] = *(const u4v*)(bb + soff);
  u4v stag = *(const u4v*)(bb + 2048 + soff);
  f4 cs0 = *(const f4*)(skh + g * 8);
  f4 cs1 = *(const f4*)(skh + g * 8 + 4);
  u4v caw = *(const u4v*)(ap);
  __syncthreads();

  for (int kb4 = 0; kb4 < 16; ++kb4) {
    u4v naw = *(const u4v*)(ap + kb4 * 4 + 4);  // kb4=15 overreads 16B in-ws
    #pragma unroll
    for (int u = 0; u < 4; ++u) {
      int kb = kb4 * 4 + u;
      // issue-early: B tile kb+2 (tail overreads stay inside ws) + next sk
      u4v nx = *(const u4v*)(bb + (kb + 2) * 2048 + soff);
      const float* nsp = skh + (kb + 1) * 32 + g * 8;
      f4 ns0 = *(const f4*)nsp;
      f4 ns1 = *(const f4*)(nsp + 4);

      u32 ab = (caw[u] >> (g * 8)) & 0xffu;
      union { s16x8 v; u32 d[4]; } af;
      {
        f4 x0 = cs0 + sdv;
        f4 x1 = cs1 + sdv;
        x0 = __builtin_elementwise_max(x0, x0 * NSLOPE);   // leaky (log2e pre-folded)
        x1 = __builtin_elementwise_max(x1, x1 * NSLOPE);
        float p[8];
        #pragma unroll
        for (int e = 0; e < 4; ++e) {
          p[e]     = __builtin_amdgcn_exp2f(x0[e]);
          p[e + 4] = __builtin_amdgcn_exp2f(x1[e]);
        }
        #pragma unroll
        for (int e = 0; e < 8; ++e) {
          int mk = __builtin_amdgcn_sbfe(ab, e, 1);        // 0 or -1
          p[e] = __uint_as_float(__float_as_uint(p[e]) & (u32)mk);
        }
        #pragma unroll
        for (int jj = 0; jj < 4; ++jj)
          asm("v_cvt_pk_bf16_f32 %0, %1, %2"
              : "=v"(af.d[jj]) : "v"(p[2 * jj]), "v"(p[2 * jj + 1]));
      }
      __syncthreads();                 // orders prev write->this read & read->overwrite
      *(u4v*)&bslot[(kb + 1) & 1][soff] = stag;            // write-late (kb=63: dead slot)
      s16x8 b0 = *(const s16x8*)&bslot[kb & 1][lane * 8];
      s16x8 b1 = *(const s16x8*)&bslot[kb & 1][512 + lane * 8];
      s16x8 b2 = *(const s16x8*)&bslot[kb & 1][1024 + lane * 8];
      s16x8 b3 = *(const s16x8*)&bslot[kb & 1][1536 + lane * 8];
      accd   = __builtin_amdgcn_mfma_f32_16x16x32_bf16(af.v, onesf, accd, 0, 0, 0);
      acc[0] = __builtin_amdgcn_mfma_f32_16x16x32_bf16(af.v, b0, acc[0], 0, 0, 0);
      acc[1] = __builtin_amdgcn_mfma_f32_16x16x32_bf16(af.v, b1, acc[1], 0, 0, 0);
      acc[2] = __builtin_amdgcn_mfma_f32_16x16x32_bf16(af.v, b2, acc[2], 0, 0, 0);
      acc[3] = __builtin_amdgcn_mfma_f32_16x16x32_bf16(af.v, b3, acc[3], 0, 0, 0);
      stag = nx;
      cs0 = ns0; cs1 = ns1;
    }
    caw = naw;
  }

  // epilogue: den for row g*4+j lives in lane g*16 reg j -> broadcast
  #pragma unroll
  for (int j = 0; j < 4; ++j) {
    float den = __shfl(accd[j], lane & 48);
    float linv = (den > 0.f) ? 1.f / den : 0.f;
    #pragma unroll
    for (int cc = 0; cc < 4; ++cc) {
      float o = acc[cc][j] * linv;
      ldshp[(w * 16 + g * 4 + j) * 64 + cc * 16 + c16] = f2bf_rne(elu1(o));
    }
  }
  __syncthreads();
  {
    int r = t >> 2, q = t & 3;           // 64 rows x 4 chunks of 16 u16
    int row = nt * 64 + r;
    u16* dst = hp + row * 512 + h * 64 + q * 16;
    const u16* src = ldshp + r * 64 + q * 16;
    *(u4v*)(dst)     = *(const u4v*)(src);
    *(u4v*)(dst + 8) = *(const u4v*)(src + 8);
  }
}

// ---------- epilogue: out_drone = hp @ Wf + bf; wave = 16 rows x 16 cols ----------
__global__ __launch_bounds__(256) void k_out(const u16* __restrict__ hp,
                                             const u16* __restrict__ wfT,
                                             const float* __restrict__ bfv,
                                             float* __restrict__ out){
  int t = threadIdx.x;
  int w = t >> 6, lane = t & 63, g = lane >> 4, c16 = lane & 15;
  int r0 = blockIdx.x * 16;  // grid 500 -> 8000 exact
  f4 acc = (f4){0.f, 0.f, 0.f, 0.f};
  const u16* ap = hp + (r0 + c16) * 512 + g * 8;
  const u16* bp = wfT + (w * 16 + c16) * 512 + g * 8;
  #pragma unroll 4
  for (int kb = 0; kb < 16; ++kb) {
    s16x8 a = *(const s16x8*)(ap + kb * 32);
    s16x8 b = *(const s16x8*)(bp + kb * 32);
    acc = __builtin_amdgcn_mfma_f32_16x16x32_bf16(a, b, acc, 0, 0, 0);
  }
  float bias = bfv[w * 16 + c16];
  #pragma unroll
  for (int j = 0; j < 4; ++j)
    out[(r0 + g * 4 + j) * HD + w * 16 + c16] = acc[j] + bias;
}

extern "C" void kernel_launch(void* const* d_in, const int* in_sizes, int n_in,
                              void* d_out, int out_size, void* d_ws, size_t ws_size,
                              hipStream_t stream) {
  const float* raw_drone = (const float*)d_in[0];
  const float* raw_dock  = (const float*)d_in[1];
  const int*   adj       = (const int*)d_in[2];
  const float* Wpd = (const float*)d_in[3];
  const float* bpd = (const float*)d_in[4];
  const float* Wpk = (const float*)d_in[5];
  const float* bpk = (const float*)d_in[6];
  const float* Wa  = (const float*)d_in[7];
  const float* a1  = (const float*)d_in[8];
  const float* a2  = (const float*)d_in[9];
  const float* Wf  = (const float*)d_in[10];
  const float* bfb = (const float*)d_in[11];
  float* out = (float*)d_out;
  float* out_hdock = out + Nd * HD;

  char* ws = (char*)d_ws;
  u16*   whkB = (u16*)(ws + WS_WHKB);
  float* skv  = (float*)(ws + WS_SK);
  float* sdv  = (float*)(ws + WS_SD);
  u32*   adjb = (u32*)(ws + WS_ADJB);
  u16*   wfT  = (u16*)(ws + WS_WFT);
  u16*   hp   = (u16*)(ws + WS_HP);

  k_prep<<<3012, 256, 0, stream>>>(raw_drone, raw_dock, adj, Wpd, bpd, Wpk, bpk,
                                   Wa, a1, a2, Wf, out_hdock, whkB, skv, sdv,
                                   adjb, wfT);
  k_attn<<<1000, 256, 0, stream>>>(sdv, skv, whkB, adjb, hp);
  k_out <<<500, 256, 0, stream>>>(hp, wfT, bfb, out);
}

// Round 20
// 98.774 us; speedup vs baseline: 1.1685x; 1.0007x over previous
//
#include <hip/hip_runtime.h>
#include <stdint.h>

#define Nd 8000
#define Nk 2000
#define FD 32
#define FK 16
#define HD 64
#define NH 8
#define KP 2048
#define NKB 64   // KP/32
#define LOG2E 1.44269504088896f
#define NSLOPE 0.2f

typedef float f4 __attribute__((ext_vector_type(4)));
typedef short s16x8 __attribute__((ext_vector_type(8)));
typedef int i4 __attribute__((ext_vector_type(4)));
typedef unsigned int u32;
typedef unsigned short u16;
typedef unsigned int u4v __attribute__((ext_vector_type(4)));

// ---- workspace layout (bytes), 16B aligned; total ~12.7 MB ----
#define WS_WHKB   0          // bf16 [8][64 kb][4 cc][64 lane][8 e] = 2 MB
#define WS_SK     2097152    // f32 [8][2048] (pre-scaled by log2e)
#define WS_SD     2162688    // f32 [8][8000] (pre-scaled by log2e)
#define WS_ADJB   2418688    // u32 [8000][64] bitmask (bit = k%32, word = k/32)
#define WS_WFT    4466688    // bf16 [64 j][512 k]
#define WS_HP     4532224    // bf16 [8000][512]

__device__ inline u16 f2bf_rne(float f){
  u32 u = __float_as_uint(f);
  u32 r = u + 0x7fffu + ((u >> 16) & 1u);
  return (u16)(r >> 16);
}
__device__ inline float elu1(float x){
  return x > 0.f ? x : (__builtin_amdgcn_exp2f(x * LOG2E) - 1.f);
}

// ---------- fused prep: [0,2000) adjb | [2000,2512) whk(+hdock,wfT) | [2512,3012) dsd ----------
__global__ __launch_bounds__(256) void k_prep(const float* __restrict__ rdrone,
                                              const float* __restrict__ rdock,
                                              const int*   __restrict__ adj,
                                              const float* __restrict__ Wpd,
                                              const float* __restrict__ bpd,
                                              const float* __restrict__ Wpk,
                                              const float* __restrict__ bpk,
                                              const float* __restrict__ Wa,
                                              const float* __restrict__ a1,
                                              const float* __restrict__ a2,
                                              const float* __restrict__ Wf,
                                              float* __restrict__ out_hdock,
                                              u16* __restrict__ whkB,
                                              float* __restrict__ sk,
                                              float* __restrict__ sd,
                                              u32* __restrict__ adjb,
                                              u16* __restrict__ wfT){
  __shared__ __align__(16) char smem[13440];
  int b = blockIdx.x;
  int t = threadIdx.x;

  if (b < 2000) {
    // ---- adj -> bitmask: ONE u32 word per thread; 8 i4 loads all in flight ----
    int W = b * 256 + t;                 // 2000*256 = 512000 = 8000*64 exact
    int n = W >> 6, c = W & 63;
    int k0 = c * 32;
    const int* rowp = adj + n * Nk;
    u32 bits = 0;
    #pragma unroll
    for (int q = 0; q < 8; ++q) {
      int kq = min(k0 + q * 4, Nk - 4);  // clamped in-bounds load
      i4 v = *(const i4*)(rowp + kq);
      bits |= (v[0] != 0 ? 1u : 0u) << (q * 4);
      bits |= (v[1] != 0 ? 1u : 0u) << (q * 4 + 1);
      bits |= (v[2] != 0 ? 1u : 0u) << (q * 4 + 2);
      bits |= (v[3] != 0 ? 1u : 0u) << (q * 4 + 3);
    }
    int rem = Nk - k0;                   // tail mask kills clamped/pad bits
    u32 tm = (rem >= 32) ? 0xFFFFFFFFu : ((rem <= 0) ? 0u : ((1u << rem) - 1u));
    adjb[W] = bits & tm;
    return;
  }
  if (b < 2512) {
    // ---- h_dock (-> output 1), WhkB bf16 fragments, sk; h==1 blocks also WfT ----
    int idx = b - 2000;
    int kt = idx & 63, h = idx >> 6;
    float* hs   = (float*)smem;            // [32][65]
    float* part = (float*)(smem + 8320);   // [32][8]
    u16*   ts   = (u16*)(smem + 9344);     // [64 f][32 k]
    if (h == 1) {
      int id = kt * 256 + t;
      #pragma unroll
      for (int i = 0; i < 2; ++i) {
        int ix = id * 2 + i;               // ix = j*512 + k
        int j = ix >> 9, k = ix & 511;
        wfT[ix] = f2bf_rne(Wf[k * HD + j]);
      }
    }
    {
      int r = t >> 3, f0 = (t & 7) * 8;
      int gk = kt * 32 + r;
      float v[8];
      if (gk < Nk) {
        const f4* rr = (const f4*)(rdock + gk * FK);   // 16 floats, 64B aligned
        f4 y0 = rr[0], y1 = rr[1], y2 = rr[2], y3 = rr[3];
        float xr[16] = {y0[0],y0[1],y0[2],y0[3], y1[0],y1[1],y1[2],y1[3],
                        y2[0],y2[1],y2[2],y2[3], y3[0],y3[1],y3[2],y3[3]};
        const f4* bq = (const f4*)(bpk + f0);
        f4 b0 = bq[0], b1 = bq[1];
        v[0]=b0[0]; v[1]=b0[1]; v[2]=b0[2]; v[3]=b0[3];
        v[4]=b1[0]; v[5]=b1[1]; v[6]=b1[2]; v[7]=b1[3];
        #pragma unroll
        for (int j = 0; j < FK; ++j) {
          const f4* wp = (const f4*)(Wpk + j * HD + f0);
          f4 w0 = wp[0], w1 = wp[1];
          float x = xr[j];
          v[0] += x*w0[0]; v[1] += x*w0[1]; v[2] += x*w0[2]; v[3] += x*w0[3];
          v[4] += x*w1[0]; v[5] += x*w1[1]; v[6] += x*w1[2]; v[7] += x*w1[3];
        }
        #pragma unroll
        for (int q = 0; q < 8; ++q) v[q] = elu1(v[q]);
        if (h == 0) {
          #pragma unroll
          for (int q = 0; q < 8; ++q) out_hdock[gk * HD + f0 + q] = v[q];
        }
      } else {
        #pragma unroll
        for (int q = 0; q < 8; ++q) v[q] = 0.f;
      }
      #pragma unroll
      for (int q = 0; q < 8; ++q) hs[r * 65 + f0 + q] = v[q];
    }
    __syncthreads();
    {
      int kl = t & 31, fq = t >> 5;
      const f4* war = (const f4*)(Wa + h * HD * HD);   // head panel, f4 units
      float acc[8];
      #pragma unroll
      for (int j = 0; j < 8; ++j) acc[j] = 0.f;
      #pragma unroll 4
      for (int d = 0; d < HD; ++d) {
        float hv = hs[kl * 65 + d];
        f4 wA = war[d * 16 + fq * 2];
        f4 wB = war[d * 16 + fq * 2 + 1];
        acc[0] += hv * wA[0]; acc[1] += hv * wA[1];
        acc[2] += hv * wA[2]; acc[3] += hv * wA[3];
        acc[4] += hv * wB[0]; acc[5] += hv * wB[1];
        acc[6] += hv * wB[2]; acc[7] += hv * wB[3];
      }
      float ps = 0.f;
      #pragma unroll
      for (int j = 0; j < 8; ++j) ps += acc[j] * a2[h * HD + fq * 8 + j];
      part[kl * 8 + fq] = ps;
      #pragma unroll
      for (int j = 0; j < 8; ++j)
        ts[(fq * 8 + j) * 32 + kl] = f2bf_rne(acc[j]);
    }
    __syncthreads();
    if (t < 32) {
      float s = 0.f;
      #pragma unroll
      for (int q = 0; q < 8; ++q) s += part[t * 8 + q];
      sk[h * KP + kt * 32 + t] = s * LOG2E;
    }
    {
      int cc = t >> 6, lane = t & 63, g = (t >> 4) & 3, c16 = t & 15;
      int f = cc * 16 + c16;
      u4v val = *(const u4v*)&ts[f * 32 + g * 8];
      *(u4v*)(whkB + (((h * NKB + kt) * 4 + cc) * 64 + lane) * 8) = val;
    }
    return;
  }
  {
    // ---- sd[h][n] = (elu(raw_drone@Wpd+bpd) . (Wa_h@a1_h)) * log2e ----
    int bid = b - 2512;
    float* wa1 = (float*)smem;             // [8][64] = 512 floats
    // parallel wa1: 8 lanes per entry, coalesced 32B slices, depth 8 not 64
    #pragma unroll
    for (int pass = 0; pass < 16; ++pass) {
      int ix = pass * 32 + (t >> 3);       // entry = h*64+d, 32 entries/pass
      int fs = (t & 7) * 8;
      const f4* wr = (const f4*)(Wa + ix * HD + fs);
      const f4* ar = (const f4*)(a1 + (ix >> 6) * HD + fs);
      f4 wv0 = wr[0], wv1 = wr[1];
      f4 av0 = ar[0], av1 = ar[1];
      float s = (wv0[0]*av0[0] + wv0[1]*av0[1]) + (wv0[2]*av0[2] + wv0[3]*av0[3])
              + (wv1[0]*av1[0] + wv1[1]*av1[1]) + (wv1[2]*av1[2] + wv1[3]*av1[3]);
      s += __shfl_xor(s, 1); s += __shfl_xor(s, 2); s += __shfl_xor(s, 4);
      if ((t & 7) == 0) wa1[ix] = s;
    }
    __syncthreads();
    int r4 = t >> 6, d = t & 63;
    for (int rr = 0; rr < 4; ++rr) {
      int n = bid * 16 + r4 * 4 + rr;      // 500*16 = 8000 exact
      const f4* rp = (const f4*)(rdrone + n * FD);   // 32 floats, 8 f4
      float xr[FD];
      #pragma unroll
      for (int q = 0; q < 8; ++q) {
        f4 xv = rp[q];
        xr[q*4+0] = xv[0]; xr[q*4+1] = xv[1]; xr[q*4+2] = xv[2]; xr[q*4+3] = xv[3];
      }
      float a0 = bpd[d], a1s = 0.f, a2s = 0.f, a3s = 0.f;
      #pragma unroll
      for (int j = 0; j < FD; j += 4) {    // 4 independent chains, coalesced Wpd
        a0  += xr[j]   * Wpd[j * HD + d];
        a1s += xr[j+1] * Wpd[(j+1) * HD + d];
        a2s += xr[j+2] * Wpd[(j+2) * HD + d];
        a3s += xr[j+3] * Wpd[(j+3) * HD + d];
      }
      float hd = elu1((a0 + a1s) + (a2s + a3s));
      #pragma unroll
      for (int h = 0; h < NH; ++h) {
        float v = hd * wa1[h * HD + d];
        v += __shfl_xor(v, 1);  v += __shfl_xor(v, 2);  v += __shfl_xor(v, 4);
        v += __shfl_xor(v, 8);  v += __shfl_xor(v, 16); v += __shfl_xor(v, 32);
        if (d == 0) sd[h * Nd + n] = v * LOG2E;
      }
    }
  }
}

// ---------- main: masked softmax(leaky(sd+sk)) @ Whk via MFMA ----------
// grid 1000 = 125 nt x 8 h (h = bid&7 pins head to XCD). Block = 64 rows,
// wave w = 16 rows, LDS 2-slot B staging (issue-early/write-late), exp2 P.
__global__ __launch_bounds__(256) void k_attn(const float* __restrict__ sd,
                                              const float* __restrict__ sk,
                                              const u16* __restrict__ whkB,
                                              const u32* __restrict__ adjb,
                                              u16* __restrict__ hp){
  int bid = blockIdx.x;
  int h = bid & 7, nt = bid >> 3;
  int t = threadIdx.x;
  int w = t >> 6, lane = t & 63, g = lane >> 4, c16 = lane & 15;
  int r0 = nt * 64 + w * 16;
  __shared__ u16 bslot[2][2048];     // 2 x 4KB B tiles
  __shared__ u16 ldshp[64 * 64];

  int rowA = r0 + c16;               // always < 8000
  float sdv = sd[h * Nd + rowA];
  f4 acc[4], accd;
  accd = (f4){0.f, 0.f, 0.f, 0.f};
  #pragma unroll
  for (int cc = 0; cc < 4; ++cc) acc[cc] = (f4){0.f, 0.f, 0.f, 0.f};
  s16x8 onesf = (s16x8)(short)((c16 == 0) ? 0x3F80 : 0);

  const u16* bb = whkB + h * (NKB * 4 * 64 * 8);
  const float* skh = sk + h * KP;
  const u32* ap = adjb + rowA * 64;
  int soff = w * 512 + lane * 8;     // this thread's stage slot offset (u16)

  // prologue: slot0 <- tile0 (direct), stag <- tile1 (regs)
  *(u4v*)&bslot[0][soff] = *(const u4v*)(bb + soff);
  u4v stag = *(const u4v*)(bb + 2048 + soff);
  f4 cs0 = *(const f4*)(skh + g * 8);
  f4 cs1 = *(const f4*)(skh + g * 8 + 4);
  u4v caw = *(const u4v*)(ap);
  __syncthreads();

  for (int kb4 = 0; kb4 < 16; ++kb4) {
    u4v naw = *(const u4v*)(ap + kb4 * 4 + 4);  // kb4=15 overreads 16B in-ws
    #pragma unroll
    for (int u = 0; u < 4; ++u) {
      int kb = kb4 * 4 + u;
      // issue-early: B tile kb+2 (tail overreads stay inside ws) + next sk
      u4v nx = *(const u4v*)(bb + (kb + 2) * 2048 + soff);
      const float* nsp = skh + (kb + 1) * 32 + g * 8;
      f4 ns0 = *(const f4*)nsp;
      f4 ns1 = *(const f4*)(nsp + 4);

      u32 ab = (caw[u] >> (g * 8)) & 0xffu;
      union { s16x8 v; u32 d[4]; } af;
      {
        f4 x0 = cs0 + sdv;
        f4 x1 = cs1 + sdv;
        x0 = __builtin_elementwise_max(x0, x0 * NSLOPE);   // leaky (log2e pre-folded)
        x1 = __builtin_elementwise_max(x1, x1 * NSLOPE);
        float p[8];
        #pragma unroll
        for (int e = 0; e < 4; ++e) {
          p[e]     = __builtin_amdgcn_exp2f(x0[e]);
          p[e + 4] = __builtin_amdgcn_exp2f(x1[e]);
        }
        #pragma unroll
        for (int e = 0; e < 8; ++e) {
          int mk = __builtin_amdgcn_sbfe(ab, e, 1);        // 0 or -1
          p[e] = __uint_as_float(__float_as_uint(p[e]) & (u32)mk);
        }
        #pragma unroll
        for (int jj = 0; jj < 4; ++jj)
          asm("v_cvt_pk_bf16_f32 %0, %1, %2"
              : "=v"(af.d[jj]) : "v"(p[2 * jj]), "v"(p[2 * jj + 1]));
      }
      __syncthreads();                 // orders prev write->this read & read->overwrite
      *(u4v*)&bslot[(kb + 1) & 1][soff] = stag;            // write-late (kb=63: dead slot)
      s16x8 b0 = *(const s16x8*)&bslot[kb & 1][lane * 8];
      s16x8 b1 = *(const s16x8*)&bslot[kb & 1][512 + lane * 8];
      s16x8 b2 = *(const s16x8*)&bslot[kb & 1][1024 + lane * 8];
      s16x8 b3 = *(const s16x8*)&bslot[kb & 1][1536 + lane * 8];
      accd   = __builtin_amdgcn_mfma_f32_16x16x32_bf16(af.v, onesf, accd, 0, 0, 0);
      acc[0] = __builtin_amdgcn_mfma_f32_16x16x32_bf16(af.v, b0, acc[0], 0, 0, 0);
      acc[1] = __builtin_amdgcn_mfma_f32_16x16x32_bf16(af.v, b1, acc[1], 0, 0, 0);
      acc[2] = __builtin_amdgcn_mfma_f32_16x16x32_bf16(af.v, b2, acc[2], 0, 0, 0);
      acc[3] = __builtin_amdgcn_mfma_f32_16x16x32_bf16(af.v, b3, acc[3], 0, 0, 0);
      stag = nx;
      cs0 = ns0; cs1 = ns1;
    }
    caw = naw;
  }

  // epilogue: den for row g*4+j lives in lane g*16 reg j -> broadcast
  #pragma unroll
  for (int j = 0; j < 4; ++j) {
    float den = __shfl(accd[j], lane & 48);
    float linv = (den > 0.f) ? 1.f / den : 0.f;
    #pragma unroll
    for (int cc = 0; cc < 4; ++cc) {
      float o = acc[cc][j] * linv;
      ldshp[(w * 16 + g * 4 + j) * 64 + cc * 16 + c16] = f2bf_rne(elu1(o));
    }
  }
  __syncthreads();
  {
    int r = t >> 2, q = t & 3;           // 64 rows x 4 chunks of 16 u16
    int row = nt * 64 + r;
    u16* dst = hp + row * 512 + h * 64 + q * 16;
    const u16* src = ldshp + r * 64 + q * 16;
    *(u4v*)(dst)     = *(const u4v*)(src);
    *(u4v*)(dst + 8) = *(const u4v*)(src + 8);
  }
}

// ---------- epilogue: out_drone = hp @ Wf + bf; wave = 16 rows x 16 cols ----------
__global__ __launch_bounds__(256) void k_out(const u16* __restrict__ hp,
                                             const u16* __restrict__ wfT,
                                             const float* __restrict__ bfv,
                                             float* __restrict__ out){
  int t = threadIdx.x;
  int w = t >> 6, lane = t & 63, g = lane >> 4, c16 = lane & 15;
  int r0 = blockIdx.x * 16;  // grid 500 -> 8000 exact
  f4 acc = (f4){0.f, 0.f, 0.f, 0.f};
  const u16* ap = hp + (r0 + c16) * 512 + g * 8;
  const u16* bp = wfT + (w * 16 + c16) * 512 + g * 8;
  #pragma unroll 4
  for (int kb = 0; kb < 16; ++kb) {
    s16x8 a = *(const s16x8*)(ap + kb * 32);
    s16x8 b = *(const s16x8*)(bp + kb * 32);
    acc = __builtin_amdgcn_mfma_f32_16x16x32_bf16(a, b, acc, 0, 0, 0);
  }
  float bias = bfv[w * 16 + c16];
  #pragma unroll
  for (int j = 0; j < 4; ++j)
    out[(r0 + g * 4 + j) * HD + w * 16 + c16] = acc[j] + bias;
}

extern "C" void kernel_launch(void* const* d_in, const int* in_sizes, int n_in,
                              void* d_out, int out_size, void* d_ws, size_t ws_size,
                              hipStream_t stream) {
  const float* raw_drone = (const float*)d_in[0];
  const float* raw_dock  = (const float*)d_in[1];
  const int*   adj       = (const int*)d_in[2];
  const float* Wpd = (const float*)d_in[3];
  const float* bpd = (const float*)d_in[4];
  const float* Wpk = (const float*)d_in[5];
  const float* bpk = (const float*)d_in[6];
  const float* Wa  = (const float*)d_in[7];
  const float* a1  = (const float*)d_in[8];
  const float* a2  = (const float*)d_in[9];
  const float* Wf  = (const float*)d_in[10];
  const float* bfb = (const float*)d_in[11];
  float* out = (float*)d_out;
  float* out_hdock = out + Nd * HD;

  char* ws = (char*)d_ws;
  u16*   whkB = (u16*)(ws + WS_WHKB);
  float* skv  = (float*)(ws + WS_SK);
  float* sdv  = (float*)(ws + WS_SD);
  u32*   adjb = (u32*)(ws + WS_ADJB);
  u16*   wfT  = (u16*)(ws + WS_WFT);
  u16*   hp   = (u16*)(ws + WS_HP);

  k_prep<<<3012, 256, 0, stream>>>(raw_drone, raw_dock, adj, Wpd, bpd, Wpk, bpk,
                                   Wa, a1, a2, Wf, out_hdock, whkB, skv, sdv,
                                   adjb, wfT);
  k_attn<<<1000, 256, 0, stream>>>(sdv, skv, whkB, adjb, hp);
  k_out <<<500, 256, 0, stream>>>(hp, wfT, bfb, out);
}